// Round 5
// baseline (104.404 us; speedup 1.0000x reference)
//
#include <hip/hip_runtime.h>

// ViewLearner edge-MLP, R5: int8-quantized per-node table to halve gather bytes.
//   K1 (node_uv): U|V = [x@W1_top + b1 | x@W1_bot] via bf16 MFMA, then per-half-row
//       symmetric int8 quantization. Q[n] = 128 B (64B U | 64B V) -- ONE cache line
//       per node. scales[n] = (su, sv) float2, 400 KB (stays L2-hot).
//   K2 (edge_out): out[e] = relu(su*qu + sv*qv) . W2 + b2, 8 lanes/edge,
//       64 B + 64 B gathered per edge (was 128+128 fp16).

typedef __attribute__((ext_vector_type(8))) short short8;
typedef __attribute__((ext_vector_type(4))) float f32x4;
typedef __attribute__((ext_vector_type(8))) signed char schar8;

__device__ __forceinline__ unsigned short f2bf_rne(float f) {
    union { float f; unsigned u; } v;
    v.f = f;
    return (unsigned short)((v.u + 0x7FFFu + ((v.u >> 16) & 1u)) >> 16);
}

#define W1T_K 72       // 64 + 8 shorts pad
#define CT_STRIDE 136  // 128 + 8 halfs pad

// ---- K1: per-node U|V table, bf16 MFMA -> int8 quantized --------------------
__global__ __launch_bounds__(256)
void node_uv(const float* __restrict__ X,
             const float* __restrict__ W1,
             const float* __restrict__ b1,
             signed char* __restrict__ Q,
             float* __restrict__ scales,
             int nnodes, int ntiles) {
    __shared__ __align__(16) unsigned short w1t[128 * W1T_K];
    __shared__ __align__(16) _Float16 cbuf[4][16 * CT_STRIDE];

    const int tid = threadIdx.x;
#pragma unroll
    for (int i = 0; i < 32; ++i) {
        int idx = tid + i * 256;  // 8192 = 128*64 elements of W1, coalesced
        int r = idx >> 6;
        int col = idx & 63;
        int k = r & 63;
        int jp = col + (r & 64);  // rows >=64 feed the V half (cols 64..127)
        w1t[jp * W1T_K + k] = f2bf_rne(W1[idx]);
    }
    __syncthreads();

    const int lane = tid & 63;
    const int wid = tid >> 6;
    const int c = lane & 15;
    const int quad = lane >> 4;

    const int t = blockIdx.x * 4 + wid;
    if (t >= ntiles) return;  // wave-uniform

    short8 bfrag[8][2];
#pragma unroll
    for (int nt = 0; nt < 8; ++nt)
#pragma unroll
        for (int kc = 0; kc < 2; ++kc)
            bfrag[nt][kc] =
                *(const short8*)&w1t[(nt * 16 + c) * W1T_K + kc * 32 + quad * 8];

    float b1v[8];
#pragma unroll
    for (int nt = 0; nt < 8; ++nt)
        b1v[nt] = (nt < 4) ? b1[nt * 16 + c] : 0.f;  // b1 folded into U only

    int n = t * 16 + c;
    n = (n < nnodes) ? n : (nnodes - 1);
    const float* xr = X + (size_t)n * 64 + quad * 8;
    f32x4 x0a = *(const f32x4*)(xr);
    f32x4 x0b = *(const f32x4*)(xr + 4);
    f32x4 x1a = *(const f32x4*)(xr + 32);
    f32x4 x1b = *(const f32x4*)(xr + 36);
    short8 a0, a1;
#pragma unroll
    for (int i = 0; i < 4; ++i) {
        a0[i] = (short)f2bf_rne(x0a[i]);
        a0[4 + i] = (short)f2bf_rne(x0b[i]);
        a1[i] = (short)f2bf_rne(x1a[i]);
        a1[4 + i] = (short)f2bf_rne(x1b[i]);
    }

    f32x4 acc[8];
#pragma unroll
    for (int nt = 0; nt < 8; ++nt) acc[nt] = (f32x4){0.f, 0.f, 0.f, 0.f};
#pragma unroll
    for (int nt = 0; nt < 8; ++nt) {
        acc[nt] = __builtin_amdgcn_mfma_f32_16x16x32_bf16(a0, bfrag[nt][0], acc[nt], 0, 0, 0);
        acc[nt] = __builtin_amdgcn_mfma_f32_16x16x32_bf16(a1, bfrag[nt][1], acc[nt], 0, 0, 0);
    }

    // Repack C layout (col=nt*16+c, row=quad*4+r) through per-wave LDS.
    _Float16* cb = cbuf[wid];
#pragma unroll
    for (int nt = 0; nt < 8; ++nt)
#pragma unroll
        for (int r = 0; r < 4; ++r)
            cb[(quad * 4 + r) * CT_STRIDE + nt * 16 + c] =
                (_Float16)(acc[nt][r] + b1v[nt]);

    __builtin_amdgcn_s_waitcnt(0);  // per-wave region; wave-synchronous readback

    // Lane (row=lane>>2, s=lane&3) owns 32 contiguous cols of its row.
    // s in {0,1}: U half; s in {2,3}: V half.
    const int row = lane >> 2;
    const int s = lane & 3;
    const _Float16* rp = &cb[row * CT_STRIDE + s * 32];
    float f[32];
#pragma unroll
    for (int i = 0; i < 32; ++i) f[i] = (float)rp[i];

    float m = 0.f;
#pragma unroll
    for (int i = 0; i < 32; ++i) m = fmaxf(m, fabsf(f[i]));
    m = fmaxf(m, __shfl_xor(m, 1));  // pair (s0,s1)->U max, (s2,s3)->V max
    m = fmaxf(m, 1e-20f);
    const float inv = 127.f / m;

    unsigned w[8];
#pragma unroll
    for (int g = 0; g < 8; ++g) {
        unsigned b = 0;
#pragma unroll
        for (int i = 0; i < 4; ++i) {
            int q = __float2int_rn(f[g * 4 + i] * inv);
            q = (q > 127) ? 127 : ((q < -127) ? -127 : q);
            b |= ((unsigned)(q & 0xFF)) << (i * 8);
        }
        w[g] = b;
    }

    const int n_row = t * 16 + row;
    uint4* qdst = (uint4*)(Q + (size_t)n_row * 128 + s * 32);
    qdst[0] = make_uint4(w[0], w[1], w[2], w[3]);
    qdst[1] = make_uint4(w[4], w[5], w[6], w[7]);

    const float sc = m * (1.f / 127.f);
    if (s == 0) scales[2 * n_row] = sc;      // su
    if (s == 2) scales[2 * n_row + 1] = sc;  // sv
}

// ---- K2: per-edge int8 gather + dequant + relu + dot(W2) --------------------
__global__ __launch_bounds__(256)
void edge_out(const int* __restrict__ eidx,
              const signed char* __restrict__ Q,
              const float* __restrict__ scales,
              const float* __restrict__ W2,
              const float* __restrict__ b2,
              float* __restrict__ out, int E) {
    int tid = blockIdx.x * 256 + threadIdx.x;
    int e = tid >> 3;  // 8 lanes per edge
    int j = tid & 7;   // hidden chunk [j*8, j*8+8)

    int src = eidx[e];
    int dst = eidx[E + e];

    schar8 qu = *(const schar8*)(Q + (size_t)src * 128 + j * 8);
    schar8 qv = *(const schar8*)(Q + (size_t)dst * 128 + 64 + j * 8);
    float su = scales[2 * src];      // broadcast within the 8-lane group
    float sv = scales[2 * dst + 1];

    f32x4 w2a = *(const f32x4*)(W2 + j * 8);
    f32x4 w2b = *(const f32x4*)(W2 + j * 8 + 4);

    float acc = 0.f;
#pragma unroll
    for (int i = 0; i < 4; ++i) {
        float h0 = fmaf((float)qu[i], su, (float)qv[i] * sv);
        float h1 = fmaf((float)qu[4 + i], su, (float)qv[4 + i] * sv);
        h0 = fmaxf(h0, 0.f);
        h1 = fmaxf(h1, 0.f);
        acc = fmaf(h0, w2a[i], acc);
        acc = fmaf(h1, w2b[i], acc);
    }
    acc += __shfl_xor(acc, 1, 8);
    acc += __shfl_xor(acc, 2, 8);
    acc += __shfl_xor(acc, 4, 8);
    if (j == 0) out[e] = acc + b2[0];
}

extern "C" void kernel_launch(void* const* d_in, const int* in_sizes, int n_in,
                              void* d_out, int out_size, void* d_ws, size_t ws_size,
                              hipStream_t stream) {
    const float* X = (const float*)d_in[0];
    const int* eidx = (const int*)d_in[1];
    const float* W1 = (const float*)d_in[2];
    const float* b1 = (const float*)d_in[3];
    const float* W2 = (const float*)d_in[4];
    const float* b2 = (const float*)d_in[5];
    float* out = (float*)d_out;

    const int nnodes = in_sizes[0] / 64;
    const int E = in_sizes[1] / 2;

    signed char* Q = (signed char*)d_ws;              // [nnodes][128] int8, 6.4 MB
    float* scales = (float*)((char*)d_ws + (size_t)nnodes * 128);  // [nnodes][2] f32

    const int ntiles = (nnodes + 15) / 16;
    node_uv<<<(ntiles + 3) / 4, 256, 0, stream>>>(X, W1, b1, Q, scales, nnodes, ntiles);

    const long long nthreads = (long long)E * 8;
    edge_out<<<(int)((nthreads + 255) / 256), 256, 0, stream>>>(eidx, Q, scales, W2, b2,
                                                               out, E);
}